// Round 1
// baseline (798.904 us; speedup 1.0000x reference)
//
#include <hip/hip_runtime.h>
#include <cstdint>
#include <cstddef>

#define N_NODES 50000
#define N_EDGES 400000
#define EN_TOT  (N_EDGES + N_NODES)
#define NC_SCAN ((N_NODES + 511) / 512)
#define NEG_SLOPE 0.2f
#define LN_EPS 1e-5f

__device__ __forceinline__ float wred_sum(float v) {
    #pragma unroll
    for (int m = 32; m; m >>= 1) v += __shfl_xor(v, m, 64);
    return v;
}

// ---------------------------------------------------------------------------
// GEMM: C[r][c] = sum_k A[r][k] * B[c][k] + bias[c]; act: 0=none, 1=gelu(erf)
// A: M x K row-major, B: Ncols x K row-major, C: M x ldc (cols covered by grid.y*64)
// ---------------------------------------------------------------------------
__global__ __launch_bounds__(256) void gemm_nt(
    const float* __restrict__ A, const float* __restrict__ B,
    const float* __restrict__ bias, float* __restrict__ C,
    int M, int K, int ldc, int act)
{
    __shared__ float As[64 * 128];
    __shared__ float Bs[64 * 128];
    const int tid = threadIdx.x;
    const int rb = blockIdx.x * 64;
    const int cb = blockIdx.y * 64;
    const int rg = tid >> 4;    // 0..15 -> rows 4*rg..4*rg+3
    const int cg = tid & 15;    // 0..15 -> cols 4*cg..4*cg+3

    float acc[4][4] = {};

    for (int k0 = 0; k0 < K; k0 += 128) {
        // stage A tile: 64 rows x 128 floats, swizzled float4 chunks
        #pragma unroll
        for (int i = 0; i < 8; ++i) {
            int fidx = tid + i * 256;        // 0..2047
            int r = fidx >> 5;               // 0..63
            int q = fidx & 31;               // float4 chunk 0..31
            int gr = rb + r;
            float4 v = make_float4(0.f, 0.f, 0.f, 0.f);
            if (gr < M) v = *(const float4*)(A + (size_t)gr * K + k0 + q * 4);
            int qs = q ^ ((r >> 2) & 7);
            *(float4*)(As + r * 128 + qs * 4) = v;
        }
        // stage B tile (cols always in range: grid.y*64 == Ncols)
        #pragma unroll
        for (int i = 0; i < 8; ++i) {
            int fidx = tid + i * 256;
            int r = fidx >> 5;
            int q = fidx & 31;
            float4 v = *(const float4*)(B + (size_t)(cb + r) * K + k0 + q * 4);
            int qs = q ^ ((r >> 2) & 7);
            *(float4*)(Bs + r * 128 + qs * 4) = v;
        }
        __syncthreads();

        #pragma unroll 8
        for (int kk = 0; kk < 128; kk += 4) {
            int q = kk >> 2;
            float4 a[4], b[4];
            #pragma unroll
            for (int i = 0; i < 4; ++i)
                a[i] = *(const float4*)(As + (4 * rg + i) * 128 + ((q ^ (rg & 7)) << 2));
            #pragma unroll
            for (int j = 0; j < 4; ++j)
                b[j] = *(const float4*)(Bs + (4 * cg + j) * 128 + ((q ^ (cg & 7)) << 2));
            #pragma unroll
            for (int i = 0; i < 4; ++i)
                #pragma unroll
                for (int j = 0; j < 4; ++j) {
                    acc[i][j] += a[i].x * b[j].x;
                    acc[i][j] += a[i].y * b[j].y;
                    acc[i][j] += a[i].z * b[j].z;
                    acc[i][j] += a[i].w * b[j].w;
                }
        }
        __syncthreads();
    }

    #pragma unroll
    for (int i = 0; i < 4; ++i) {
        int r = rb + 4 * rg + i;
        if (r >= M) continue;
        #pragma unroll
        for (int j = 0; j < 4; ++j) {
            int c = cb + 4 * cg + j;
            float v = acc[i][j] + bias[c];
            if (act == 1) v = v * 0.5f * (1.0f + erff(v * 0.70710678118654752f));
            C[(size_t)r * ldc + c] = v;
        }
    }
}

// ---------------------------------------------------------------------------
// CSR build
// ---------------------------------------------------------------------------
__global__ __launch_bounds__(256) void count_deg(const int* __restrict__ dst,
                                                 int* __restrict__ counts)
{
    int i = blockIdx.x * 256 + threadIdx.x;
    if (i >= EN_TOT) return;
    int d = (i < N_EDGES) ? dst[i] : (i - N_EDGES);
    atomicAdd(counts + d, 1);
}

__global__ __launch_bounds__(64) void scan1(const int* __restrict__ counts,
                                            int* __restrict__ csum)
{
    int lane = threadIdx.x;
    int base = blockIdx.x * 512 + lane * 8;
    int s = 0;
    #pragma unroll
    for (int k = 0; k < 8; ++k) {
        int idx = base + k;
        if (idx < N_NODES) s += counts[idx];
    }
    #pragma unroll
    for (int m = 32; m; m >>= 1) s += __shfl_xor(s, m, 64);
    if (lane == 0) csum[blockIdx.x] = s;
}

__global__ void scan2(int* __restrict__ csum, int* __restrict__ offs)
{
    if (threadIdx.x == 0 && blockIdx.x == 0) {
        int run = 0;
        for (int c = 0; c < NC_SCAN; ++c) { int t = csum[c]; csum[c] = run; run += t; }
        offs[N_NODES] = run;   // == EN_TOT
    }
}

__global__ __launch_bounds__(64) void scan3(const int* __restrict__ counts,
                                            const int* __restrict__ csum,
                                            int* __restrict__ offs)
{
    int lane = threadIdx.x;
    int base = blockIdx.x * 512 + lane * 8;
    int cnt[8];
    int s = 0;
    #pragma unroll
    for (int k = 0; k < 8; ++k) {
        int idx = base + k;
        cnt[k] = (idx < N_NODES) ? counts[idx] : 0;
        s += cnt[k];
    }
    int inc = s;
    #pragma unroll
    for (int d = 1; d < 64; d <<= 1) {
        int t = __shfl_up(inc, d, 64);
        if (lane >= d) inc += t;
    }
    int run = csum[blockIdx.x] + (inc - s);
    #pragma unroll
    for (int k = 0; k < 8; ++k) {
        int idx = base + k;
        if (idx < N_NODES) { offs[idx] = run; run += cnt[k]; }
    }
}

__global__ __launch_bounds__(256) void scatter_edges(
    const int* __restrict__ src, const int* __restrict__ dst,
    const int* __restrict__ offs, int* __restrict__ cursor,
    int* __restrict__ srcList)
{
    int i = blockIdx.x * 256 + threadIdx.x;
    if (i >= EN_TOT) return;
    int s, d;
    if (i < N_EDGES) { s = src[i]; d = dst[i]; }
    else             { s = d = i - N_EDGES; }
    int pos = atomicAdd(cursor + d, 1);
    srcList[offs[d] + pos] = s;
}

// ---------------------------------------------------------------------------
// GATv2 per destination node (one wave each): online softmax over incident
// edges + head-mean + bias + residual + LayerNorm1  ->  x1
// ---------------------------------------------------------------------------
__global__ __launch_bounds__(256) void gat_fused(
    const float* __restrict__ x, const float* __restrict__ xl,
    const float* __restrict__ xr, const int* __restrict__ offs,
    const int* __restrict__ srcList, const float* __restrict__ att,
    const float* __restrict__ bias, const float* __restrict__ g1,
    const float* __restrict__ be1, float* __restrict__ x1)
{
    int wave = threadIdx.x >> 6;
    int lane = threadIdx.x & 63;
    int v = blockIdx.x * 4 + wave;
    if (v >= N_NODES) return;

    const float* xrv = xr + (size_t)v * 512;
    float r0[4], r1[4], av0[4], av1[4];
    #pragma unroll
    for (int h = 0; h < 4; ++h) {
        r0[h]  = xrv[h * 128 + lane];
        r1[h]  = xrv[h * 128 + lane + 64];
        av0[h] = att[h * 128 + lane];
        av1[h] = att[h * 128 + lane + 64];
    }

    float mh[4], lh[4], a0[4], a1[4];
    #pragma unroll
    for (int h = 0; h < 4; ++h) { mh[h] = -3.4e38f; lh[h] = 0.f; a0[h] = 0.f; a1[h] = 0.f; }

    int jb = offs[v], je = offs[v + 1];
    for (int j = jb; j < je; ++j) {
        int u = srcList[j];
        const float* xlu = xl + (size_t)u * 512;
        #pragma unroll
        for (int h = 0; h < 4; ++h) {
            float b0 = xlu[h * 128 + lane];
            float b1 = xlu[h * 128 + lane + 64];
            float s0 = b0 + r0[h];
            float s1 = b1 + r1[h];
            float p0 = (s0 > 0.f) ? s0 : NEG_SLOPE * s0;
            float p1 = (s1 > 0.f) ? s1 : NEG_SLOPE * s1;
            float e = wred_sum(p0 * av0[h] + p1 * av1[h]);
            float nm = fmaxf(mh[h], e);
            float sc = __expf(mh[h] - nm);   // first edge: exp(-inf) = 0
            float w  = __expf(e - nm);
            lh[h] = lh[h] * sc + w;
            a0[h] = a0[h] * sc + w * b0;
            a1[h] = a1[h] * sc + w * b1;
            mh[h] = nm;
        }
    }

    float o0 = 0.f, o1 = 0.f;
    #pragma unroll
    for (int h = 0; h < 4; ++h) { o0 += a0[h] / lh[h]; o1 += a1[h] / lh[h]; }
    o0 = o0 * 0.25f + bias[lane];
    o1 = o1 * 0.25f + bias[lane + 64];

    size_t xo = (size_t)v * 128;
    float y0 = x[xo + lane] + o0;
    float y1 = x[xo + lane + 64] + o1;

    float mu = wred_sum(y0 + y1) * (1.0f / 128.0f);
    float d0 = y0 - mu, d1 = y1 - mu;
    float var = wred_sum(d0 * d0 + d1 * d1) * (1.0f / 128.0f);
    float rs = rsqrtf(var + LN_EPS);
    x1[xo + lane]      = d0 * rs * g1[lane]      + be1[lane];
    x1[xo + lane + 64] = d1 * rs * g1[lane + 64] + be1[lane + 64];
}

// ---------------------------------------------------------------------------
// residual + LayerNorm2 -> out
// ---------------------------------------------------------------------------
__global__ __launch_bounds__(256) void resid_ln(
    const float* __restrict__ xa, const float* __restrict__ xb,
    const float* __restrict__ g, const float* __restrict__ b,
    float* __restrict__ out)
{
    int wave = threadIdx.x >> 6;
    int lane = threadIdx.x & 63;
    int v = blockIdx.x * 4 + wave;
    if (v >= N_NODES) return;
    size_t o = (size_t)v * 128;
    float y0 = xa[o + lane]      + xb[o + lane];
    float y1 = xa[o + lane + 64] + xb[o + lane + 64];
    float mu = wred_sum(y0 + y1) * (1.0f / 128.0f);
    float d0 = y0 - mu, d1 = y1 - mu;
    float var = wred_sum(d0 * d0 + d1 * d1) * (1.0f / 128.0f);
    float rs = rsqrtf(var + LN_EPS);
    out[o + lane]      = d0 * rs * g[lane]      + b[lane];
    out[o + lane + 64] = d1 * rs * g[lane + 64] + b[lane + 64];
}

// ---------------------------------------------------------------------------
extern "C" void kernel_launch(void* const* d_in, const int* in_sizes, int n_in,
                              void* d_out, int out_size, void* d_ws, size_t ws_size,
                              hipStream_t stream)
{
    const float* x    = (const float*)d_in[0];
    const int*   ei   = (const int*)  d_in[1];
    const float* Wl   = (const float*)d_in[2];
    const float* bl   = (const float*)d_in[3];
    const float* Wr   = (const float*)d_in[4];
    const float* br   = (const float*)d_in[5];
    const float* att  = (const float*)d_in[6];
    const float* bias = (const float*)d_in[7];
    const float* g1   = (const float*)d_in[8];
    const float* be1  = (const float*)d_in[9];
    const float* W1   = (const float*)d_in[10];
    const float* b1   = (const float*)d_in[11];
    const float* W2   = (const float*)d_in[12];
    const float* b2   = (const float*)d_in[13];
    const float* g2   = (const float*)d_in[14];
    const float* be2  = (const float*)d_in[15];
    float* out = (float*)d_out;

    char* ws = (char*)d_ws;
    size_t off = 0;
    auto alloc = [&](size_t bytes) -> void* {
        void* p = ws + off;
        off = (off + bytes + 255) & ~(size_t)255;
        return p;
    };
    float* xl      = (float*)alloc((size_t)N_NODES * 512 * 4);
    float* xr      = (float*)alloc((size_t)N_NODES * 512 * 4);
    float* x1      = (float*)alloc((size_t)N_NODES * 128 * 4);
    int*   offs    = (int*)  alloc((size_t)(N_NODES + 1) * 4);
    int*   counts  = (int*)  alloc((size_t)N_NODES * 4 * 2);  // counts + cursor
    int*   cursor  = counts + N_NODES;
    int*   csum    = (int*)  alloc(512);
    int*   srcList = (int*)  alloc((size_t)EN_TOT * 4);
    float* t = xr;  // reuse xr region after gat_fused (51.2MB <= 102.4MB)
    float* f = xl;  // reuse xl region after gat_fused

    hipMemsetAsync(counts, 0, (size_t)N_NODES * 8, stream);

    gemm_nt<<<dim3(782, 8), 256, 0, stream>>>(x, Wl, bl, xl, N_NODES, 128, 512, 0);
    gemm_nt<<<dim3(782, 8), 256, 0, stream>>>(x, Wr, br, xr, N_NODES, 128, 512, 0);

    count_deg<<<(EN_TOT + 255) / 256, 256, 0, stream>>>(ei + N_EDGES, counts);
    scan1<<<NC_SCAN, 64, 0, stream>>>(counts, csum);
    scan2<<<1, 64, 0, stream>>>(csum, offs);
    scan3<<<NC_SCAN, 64, 0, stream>>>(counts, csum, offs);
    scatter_edges<<<(EN_TOT + 255) / 256, 256, 0, stream>>>(ei, ei + N_EDGES, offs,
                                                           cursor, srcList);

    gat_fused<<<12500, 256, 0, stream>>>(x, xl, xr, offs, srcList, att, bias,
                                         g1, be1, x1);

    gemm_nt<<<dim3(782, 4), 256, 0, stream>>>(x1, W1, b1, t, N_NODES, 128, 256, 1);
    gemm_nt<<<dim3(782, 2), 256, 0, stream>>>(t, W2, b2, f, N_NODES, 256, 128, 0);

    resid_ln<<<12500, 256, 0, stream>>>(x1, f, g2, be2, out);
}

// Round 2
// 408.111 us; speedup vs baseline: 1.9576x; 1.9576x over previous
//
#include <hip/hip_runtime.h>
#include <cstdint>
#include <cstddef>

#define N_NODES 50000
#define N_EDGES 400000
#define EN_TOT  (N_EDGES + N_NODES)
#define NC_SCAN ((N_NODES + 511) / 512)   // 98
#define NEG_SLOPE 0.2f
#define LN_EPS 1e-5f

typedef short bf16x8 __attribute__((ext_vector_type(8)));
typedef float f32x4  __attribute__((ext_vector_type(4)));

__device__ __forceinline__ ushort f2bf(float f) {
    union { float f; uint32_t u; } c; c.f = f;
    uint32_t u = c.u + 0x7FFFu + ((c.u >> 16) & 1u);   // RNE
    return (ushort)(u >> 16);
}
__device__ __forceinline__ float bf_lo(uint32_t u) {
    union { uint32_t u; float f; } c; c.u = u << 16; return c.f;
}
__device__ __forceinline__ float bf_hi(uint32_t u) {
    union { uint32_t u; float f; } c; c.u = u & 0xFFFF0000u; return c.f;
}

// ---------------------------------------------------------------------------
// fp32 -> bf16 casts
// ---------------------------------------------------------------------------
__global__ __launch_bounds__(256) void cast_x(const float* __restrict__ x,
                                              ushort* __restrict__ xb)
{
    int i = blockIdx.x * 256 + threadIdx.x;          // float4 index, exact cover
    float4 v = ((const float4*)x)[i];
    ushort4 o;
    o.x = f2bf(v.x); o.y = f2bf(v.y); o.z = f2bf(v.z); o.w = f2bf(v.w);
    ((ushort4*)xb)[i] = o;
}

// wb layout: [Wl 65536 | Wr 65536 | W1 32768 | W2 32768 | att 512]
__global__ __launch_bounds__(256) void cast_weights(
    const float* __restrict__ Wl, const float* __restrict__ Wr,
    const float* __restrict__ W1, const float* __restrict__ W2,
    const float* __restrict__ att, ushort* __restrict__ wb)
{
    int i = blockIdx.x * 256 + threadIdx.x;          // 770*256 == 197120 exact
    const float* src; int off;
    if (i < 65536)       { src = Wl;  off = i; }
    else if (i < 131072) { src = Wr;  off = i - 65536; }
    else if (i < 163840) { src = W1;  off = i - 131072; }
    else if (i < 196608) { src = W2;  off = i - 163840; }
    else                 { src = att; off = i - 196608; }
    wb[i] = f2bf(src[off]);
}

// ---------------------------------------------------------------------------
// bf16 MFMA GEMM: C[r][c] = sum_k A[r][k]*B[c][k] + bias[c]
// A: M x K bf16 row-major, B: N x K bf16 row-major (N = gridDim.y*128)
// act: 1 = exact GELU.  outbf: 1 = bf16 output, else fp32.
// Block 256 = 4 waves in 2x2; 128x128 tile; K staged in 128-chunks.
// ---------------------------------------------------------------------------
__global__ __launch_bounds__(256) void gemm_bf16(
    const ushort* __restrict__ A, const ushort* __restrict__ B,
    const float* __restrict__ bias, void* __restrict__ Cout,
    int M, int K, int ldc, int act, int outbf)
{
    __shared__ ushort As[128 * 128];   // 32 KB, XOR-swizzled 16B chunks
    __shared__ ushort Bs[128 * 128];
    const int tid  = threadIdx.x;
    const int rb   = blockIdx.x * 128;
    const int cb   = blockIdx.y * 128;
    const int wave = tid >> 6;
    const int lane = tid & 63;
    const int wm   = (wave >> 1) * 64;
    const int wn   = (wave & 1) * 64;
    const int lr   = lane & 15;        // row-in-16 (A) / col (B) / D col
    const int lq   = lane >> 4;        // k-group / D row-group

    f32x4 zero = {0.f, 0.f, 0.f, 0.f};
    f32x4 acc[4][4];
    #pragma unroll
    for (int i = 0; i < 4; ++i)
        #pragma unroll
        for (int j = 0; j < 4; ++j) acc[i][j] = zero;

    for (int k0 = 0; k0 < K; k0 += 128) {
        #pragma unroll
        for (int i = 0; i < 8; ++i) {
            int chunk = tid + i * 256;     // 0..2047 16B-chunks
            int rr = chunk >> 4;           // 0..127
            int cc = chunk & 15;
            int sw = ((cc ^ (rr & 15)) * 8);
            int gr = rb + rr;
            uint4 va = make_uint4(0u, 0u, 0u, 0u);
            if (gr < M) va = *(const uint4*)(A + (size_t)gr * K + k0 + cc * 8);
            *(uint4*)(As + rr * 128 + sw) = va;
            uint4 vb = *(const uint4*)(B + (size_t)(cb + rr) * K + k0 + cc * 8);
            *(uint4*)(Bs + rr * 128 + sw) = vb;
        }
        __syncthreads();

        #pragma unroll
        for (int q = 0; q < 4; ++q) {
            int csw = ((q * 4 + lq) ^ lr) * 8;
            bf16x8 af[4], bfr[4];
            #pragma unroll
            for (int i = 0; i < 4; ++i) {
                af[i]  = *(const bf16x8*)(As + (wm + i * 16 + lr) * 128 + csw);
                bfr[i] = *(const bf16x8*)(Bs + (wn + i * 16 + lr) * 128 + csw);
            }
            #pragma unroll
            for (int i = 0; i < 4; ++i)
                #pragma unroll
                for (int j = 0; j < 4; ++j)
                    acc[i][j] = __builtin_amdgcn_mfma_f32_16x16x32_bf16(
                        af[i], bfr[j], acc[i][j], 0, 0, 0);
        }
        __syncthreads();
    }

    #pragma unroll
    for (int i = 0; i < 4; ++i) {
        int row0 = rb + wm + i * 16 + lq * 4;
        #pragma unroll
        for (int j = 0; j < 4; ++j) {
            int col = cb + wn + j * 16 + lr;
            float bv = bias[col];
            #pragma unroll
            for (int rg = 0; rg < 4; ++rg) {
                int rr = row0 + rg;
                if (rr >= M) continue;
                float v = acc[i][j][rg] + bv;
                if (act) v = v * 0.5f * (1.0f + erff(v * 0.70710678118654752f));
                if (outbf) ((ushort*)Cout)[(size_t)rr * ldc + col] = f2bf(v);
                else       ((float*) Cout)[(size_t)rr * ldc + col] = v;
            }
        }
    }
}

// ---------------------------------------------------------------------------
// CSR build
// ---------------------------------------------------------------------------
__global__ __launch_bounds__(256) void count_deg(const int* __restrict__ dst,
                                                 int* __restrict__ counts)
{
    int i = blockIdx.x * 256 + threadIdx.x;
    if (i >= EN_TOT) return;
    int d = (i < N_EDGES) ? dst[i] : (i - N_EDGES);
    atomicAdd(counts + d, 1);
}

__global__ __launch_bounds__(64) void scan1(const int* __restrict__ counts,
                                            int* __restrict__ csum)
{
    int lane = threadIdx.x;
    int base = blockIdx.x * 512 + lane * 8;
    int s = 0;
    #pragma unroll
    for (int k = 0; k < 8; ++k) {
        int idx = base + k;
        if (idx < N_NODES) s += counts[idx];
    }
    #pragma unroll
    for (int m = 32; m; m >>= 1) s += __shfl_xor(s, m, 64);
    if (lane == 0) csum[blockIdx.x] = s;
}

__global__ __launch_bounds__(64) void scan2(int* __restrict__ csum,
                                            int* __restrict__ offs)
{
    int l = threadIdx.x;
    int v0 = (l < NC_SCAN) ? csum[l] : 0;
    int v1 = (l + 64 < NC_SCAN) ? csum[l + 64] : 0;
    int s0 = v0;
    #pragma unroll
    for (int d = 1; d < 64; d <<= 1) {
        int t = __shfl_up(s0, d, 64);
        if (l >= d) s0 += t;
    }
    int tot0 = __shfl(s0, 63, 64);
    int s1 = v1;
    #pragma unroll
    for (int d = 1; d < 64; d <<= 1) {
        int t = __shfl_up(s1, d, 64);
        if (l >= d) s1 += t;
    }
    int tot1 = __shfl(s1, 63, 64);
    if (l < NC_SCAN) csum[l] = s0 - v0;
    if (l + 64 < NC_SCAN) csum[l + 64] = tot0 + s1 - v1;
    if (l == 0) offs[N_NODES] = tot0 + tot1;
}

__global__ __launch_bounds__(64) void scan3(const int* __restrict__ counts,
                                            const int* __restrict__ csum,
                                            int* __restrict__ offs)
{
    int lane = threadIdx.x;
    int base = blockIdx.x * 512 + lane * 8;
    int cnt[8];
    int s = 0;
    #pragma unroll
    for (int k = 0; k < 8; ++k) {
        int idx = base + k;
        cnt[k] = (idx < N_NODES) ? counts[idx] : 0;
        s += cnt[k];
    }
    int inc = s;
    #pragma unroll
    for (int d = 1; d < 64; d <<= 1) {
        int t = __shfl_up(inc, d, 64);
        if (lane >= d) inc += t;
    }
    int run = csum[blockIdx.x] + (inc - s);
    #pragma unroll
    for (int k = 0; k < 8; ++k) {
        int idx = base + k;
        if (idx < N_NODES) { offs[idx] = run; run += cnt[k]; }
    }
}

__global__ __launch_bounds__(256) void scatter_edges(
    const int* __restrict__ src, const int* __restrict__ dst,
    const int* __restrict__ offs, int* __restrict__ cursor,
    int* __restrict__ srcList)
{
    int i = blockIdx.x * 256 + threadIdx.x;
    if (i >= EN_TOT) return;
    int s, d;
    if (i < N_EDGES) { s = src[i]; d = dst[i]; }
    else             { s = d = i - N_EDGES; }
    int pos = atomicAdd(cursor + d, 1);
    srcList[offs[d] + pos] = s;
}

// ---------------------------------------------------------------------------
// GATv2 per destination node (one wave each), bf16 gather.
// Lane l handles head (l>>4), dims (l&15)*8 .. +7 -> one 16B load per edge.
// No-max softmax (e bounded), quarter-wave reduce, + residual + LN1.
// Writes x1 (fp32, for residual) and x1b (bf16, FFN input).
// ---------------------------------------------------------------------------
__global__ __launch_bounds__(256) void gat_fused(
    const float* __restrict__ x, const ushort* __restrict__ xl,
    const ushort* __restrict__ xr, const int* __restrict__ offs,
    const int* __restrict__ srcList, const ushort* __restrict__ attb,
    const float* __restrict__ bias, const float* __restrict__ g1,
    const float* __restrict__ be1, float* __restrict__ x1,
    ushort* __restrict__ x1b)
{
    const int wave = threadIdx.x >> 6;
    const int lane = threadIdx.x & 63;
    const int v = blockIdx.x * 4 + wave;
    if (v >= N_NODES) return;

    uint4 rw = *(const uint4*)(xr + (size_t)v * 512 + lane * 8);
    uint4 aw = *(const uint4*)(attb + lane * 8);
    float r[8], at[8];
    r[0]=bf_lo(rw.x); r[1]=bf_hi(rw.x); r[2]=bf_lo(rw.y); r[3]=bf_hi(rw.y);
    r[4]=bf_lo(rw.z); r[5]=bf_hi(rw.z); r[6]=bf_lo(rw.w); r[7]=bf_hi(rw.w);
    at[0]=bf_lo(aw.x); at[1]=bf_hi(aw.x); at[2]=bf_lo(aw.y); at[3]=bf_hi(aw.y);
    at[4]=bf_lo(aw.z); at[5]=bf_hi(aw.z); at[6]=bf_lo(aw.w); at[7]=bf_hi(aw.w);

    float acc[8] = {0.f,0.f,0.f,0.f,0.f,0.f,0.f,0.f};
    float lh = 0.f;

    const int jb = offs[v], je = offs[v + 1];
    uint4 cur = *(const uint4*)(xl + (size_t)srcList[jb] * 512 + lane * 8);
    for (int j = jb; j < je; ++j) {
        int jn = (j + 1 < je) ? (j + 1) : j;
        uint4 nxt = *(const uint4*)(xl + (size_t)srcList[jn] * 512 + lane * 8);

        float b[8];
        b[0]=bf_lo(cur.x); b[1]=bf_hi(cur.x); b[2]=bf_lo(cur.y); b[3]=bf_hi(cur.y);
        b[4]=bf_lo(cur.z); b[5]=bf_hi(cur.z); b[6]=bf_lo(cur.w); b[7]=bf_hi(cur.w);
        float p = 0.f;
        #pragma unroll
        for (int k = 0; k < 8; ++k) {
            float s  = b[k] + r[k];
            float lr2 = fmaxf(s, 0.f) + NEG_SLOPE * fminf(s, 0.f);
            p = fmaf(lr2, at[k], p);
        }
        p += __shfl_xor(p, 1, 64);
        p += __shfl_xor(p, 2, 64);
        p += __shfl_xor(p, 4, 64);
        p += __shfl_xor(p, 8, 64);
        float w = __expf(p);
        lh += w;
        #pragma unroll
        for (int k = 0; k < 8; ++k) acc[k] = fmaf(w, b[k], acc[k]);
        cur = nxt;
    }

    const float inv = 1.0f / lh;
    const int d0 = (lane & 15) * 8;
    const size_t xo = (size_t)v * 128 + d0;

    float4 xv0 = *(const float4*)(x + xo);
    float4 xv1 = *(const float4*)(x + xo + 4);
    float4 bb0 = *(const float4*)(bias + d0);
    float4 bb1 = *(const float4*)(bias + d0 + 4);
    float xr8[8] = {xv0.x,xv0.y,xv0.z,xv0.w,xv1.x,xv1.y,xv1.z,xv1.w};
    float bi8[8] = {bb0.x,bb0.y,bb0.z,bb0.w,bb1.x,bb1.y,bb1.z,bb1.w};

    float y[8];
    float s = 0.f;
    #pragma unroll
    for (int k = 0; k < 8; ++k) {
        float o = acc[k] * inv;                 // this head's alpha-weighted sum
        o += __shfl_xor(o, 16, 64);             // sum across heads
        o += __shfl_xor(o, 32, 64);
        float yy = xr8[k] + o * 0.25f + bi8[k]; // head mean + bias + residual
        y[k] = yy;
        s += yy;
    }
    s += __shfl_xor(s, 1, 64);
    s += __shfl_xor(s, 2, 64);
    s += __shfl_xor(s, 4, 64);
    s += __shfl_xor(s, 8, 64);
    float mu = s * (1.0f / 128.0f);
    float ss = 0.f;
    #pragma unroll
    for (int k = 0; k < 8; ++k) { float d = y[k] - mu; ss += d * d; }
    ss += __shfl_xor(ss, 1, 64);
    ss += __shfl_xor(ss, 2, 64);
    ss += __shfl_xor(ss, 4, 64);
    ss += __shfl_xor(ss, 8, 64);
    float rs = rsqrtf(ss * (1.0f / 128.0f) + LN_EPS);

    if ((lane >> 4) == 0) {                     // quarters hold identical y
        float4 g0 = *(const float4*)(g1 + d0);
        float4 g4 = *(const float4*)(g1 + d0 + 4);
        float4 e0 = *(const float4*)(be1 + d0);
        float4 e4 = *(const float4*)(be1 + d0 + 4);
        float gg[8] = {g0.x,g0.y,g0.z,g0.w,g4.x,g4.y,g4.z,g4.w};
        float ee[8] = {e0.x,e0.y,e0.z,e0.w,e4.x,e4.y,e4.z,e4.w};
        float z[8];
        ushort4 zb0, zb1;
        #pragma unroll
        for (int k = 0; k < 8; ++k) z[k] = (y[k] - mu) * rs * gg[k] + ee[k];
        *(float4*)(x1 + xo)     = make_float4(z[0], z[1], z[2], z[3]);
        *(float4*)(x1 + xo + 4) = make_float4(z[4], z[5], z[6], z[7]);
        zb0.x=f2bf(z[0]); zb0.y=f2bf(z[1]); zb0.z=f2bf(z[2]); zb0.w=f2bf(z[3]);
        zb1.x=f2bf(z[4]); zb1.y=f2bf(z[5]); zb1.z=f2bf(z[6]); zb1.w=f2bf(z[7]);
        *(ushort4*)(x1b + xo)     = zb0;
        *(ushort4*)(x1b + xo + 4) = zb1;
    }
}

// ---------------------------------------------------------------------------
// residual + LayerNorm2 -> out
// ---------------------------------------------------------------------------
__device__ __forceinline__ float wred_sum(float v) {
    #pragma unroll
    for (int m = 32; m; m >>= 1) v += __shfl_xor(v, m, 64);
    return v;
}

__global__ __launch_bounds__(256) void resid_ln(
    const float* __restrict__ xa, const float* __restrict__ xb,
    const float* __restrict__ g, const float* __restrict__ b,
    float* __restrict__ out)
{
    int wave = threadIdx.x >> 6;
    int lane = threadIdx.x & 63;
    int v = blockIdx.x * 4 + wave;
    if (v >= N_NODES) return;
    size_t o = (size_t)v * 128;
    float y0 = xa[o + lane]      + xb[o + lane];
    float y1 = xa[o + lane + 64] + xb[o + lane + 64];
    float mu = wred_sum(y0 + y1) * (1.0f / 128.0f);
    float d0 = y0 - mu, d1 = y1 - mu;
    float var = wred_sum(d0 * d0 + d1 * d1) * (1.0f / 128.0f);
    float rs = rsqrtf(var + LN_EPS);
    out[o + lane]      = d0 * rs * g[lane]      + b[lane];
    out[o + lane + 64] = d1 * rs * g[lane + 64] + b[lane + 64];
}

// ---------------------------------------------------------------------------
extern "C" void kernel_launch(void* const* d_in, const int* in_sizes, int n_in,
                              void* d_out, int out_size, void* d_ws, size_t ws_size,
                              hipStream_t stream)
{
    const float* x    = (const float*)d_in[0];
    const int*   ei   = (const int*)  d_in[1];
    const float* Wl   = (const float*)d_in[2];
    const float* bl   = (const float*)d_in[3];
    const float* Wr   = (const float*)d_in[4];
    const float* br   = (const float*)d_in[5];
    const float* att  = (const float*)d_in[6];
    const float* bias = (const float*)d_in[7];
    const float* g1   = (const float*)d_in[8];
    const float* be1  = (const float*)d_in[9];
    const float* W1   = (const float*)d_in[10];
    const float* b1   = (const float*)d_in[11];
    const float* W2   = (const float*)d_in[12];
    const float* b2   = (const float*)d_in[13];
    const float* g2   = (const float*)d_in[14];
    const float* be2  = (const float*)d_in[15];
    float* out = (float*)d_out;

    char* ws = (char*)d_ws;
    size_t off = 0;
    auto alloc = [&](size_t bytes) -> void* {
        void* p = ws + off;
        off = (off + bytes + 255) & ~(size_t)255;
        return p;
    };
    ushort* xb   = (ushort*)alloc((size_t)N_NODES * 128 * 2);
    ushort* xlb  = (ushort*)alloc((size_t)N_NODES * 512 * 2);
    ushort* xrb  = (ushort*)alloc((size_t)N_NODES * 512 * 2);
    float*  x1   = (float*) alloc((size_t)N_NODES * 128 * 4);
    ushort* x1b  = (ushort*)alloc((size_t)N_NODES * 128 * 2);
    ushort* tb   = (ushort*)alloc((size_t)N_NODES * 256 * 2);
    float*  f    = (float*) alloc((size_t)N_NODES * 128 * 4);
    ushort* wb   = (ushort*)alloc((size_t)197120 * 2);
    int*   offs    = (int*)alloc((size_t)(N_NODES + 1) * 4);
    int*   counts  = (int*)alloc((size_t)N_NODES * 4 * 2);
    int*   cursor  = counts + N_NODES;
    int*   csum    = (int*)alloc(512);
    int*   srcList = (int*)alloc((size_t)EN_TOT * 4);

    ushort* wlb  = wb;
    ushort* wrb  = wb + 65536;
    ushort* w1b  = wb + 131072;
    ushort* w2b  = wb + 163840;
    ushort* attb = wb + 196608;

    hipMemsetAsync(counts, 0, (size_t)N_NODES * 8, stream);

    cast_x<<<6250, 256, 0, stream>>>(x, xb);
    cast_weights<<<770, 256, 0, stream>>>(Wl, Wr, W1, W2, att, wb);

    gemm_bf16<<<dim3(391, 4), 256, 0, stream>>>(xb, wlb, bl, xlb,
                                                N_NODES, 128, 512, 0, 1);
    gemm_bf16<<<dim3(391, 4), 256, 0, stream>>>(xb, wrb, br, xrb,
                                                N_NODES, 128, 512, 0, 1);

    count_deg<<<(EN_TOT + 255) / 256, 256, 0, stream>>>(ei + N_EDGES, counts);
    scan1<<<NC_SCAN, 64, 0, stream>>>(counts, csum);
    scan2<<<1, 64, 0, stream>>>(csum, offs);
    scan3<<<NC_SCAN, 64, 0, stream>>>(counts, csum, offs);
    scatter_edges<<<(EN_TOT + 255) / 256, 256, 0, stream>>>(ei, ei + N_EDGES,
                                                           offs, cursor, srcList);

    gat_fused<<<12500, 256, 0, stream>>>(x, xlb, xrb, offs, srcList, attb,
                                         bias, g1, be1, x1, x1b);

    gemm_bf16<<<dim3(391, 2), 256, 0, stream>>>(x1b, w1b, b1, tb,
                                                N_NODES, 128, 256, 1, 1);
    gemm_bf16<<<dim3(391, 1), 256, 0, stream>>>(tb, w2b, b2, f,
                                                N_NODES, 256, 128, 0, 0);

    resid_ln<<<12500, 256, 0, stream>>>(x1, f, g2, be2, out);
}

// Round 3
// 323.729 us; speedup vs baseline: 2.4678x; 1.2607x over previous
//
#include <hip/hip_runtime.h>
#include <cstdint>
#include <cstddef>

#define N_NODES 50000
#define N_EDGES 400000
#define EN_TOT  (N_EDGES + N_NODES)
#define NC_SCAN ((N_NODES + 511) / 512)   // 98
#define NEG_SLOPE 0.2f
#define LN_EPS 1e-5f

typedef short bf16x8 __attribute__((ext_vector_type(8)));
typedef float f32x4  __attribute__((ext_vector_type(4)));

__device__ __forceinline__ ushort f2bf(float f) {
    union { float f; uint32_t u; } c; c.f = f;
    uint32_t u = c.u + 0x7FFFu + ((c.u >> 16) & 1u);   // RNE
    return (ushort)(u >> 16);
}
__device__ __forceinline__ uint32_t pk2(float a, float b) {
    return (uint32_t)f2bf(a) | ((uint32_t)f2bf(b) << 16);
}
__device__ __forceinline__ float bf_lo(uint32_t u) {
    union { uint32_t u; float f; } c; c.u = u << 16; return c.f;
}
__device__ __forceinline__ float bf_hi(uint32_t u) {
    union { uint32_t u; float f; } c; c.u = u & 0xFFFF0000u; return c.f;
}

// ---------------------------------------------------------------------------
// weights -> bf16.  wb layout: [Wl 65536 | Wr 65536 | W1 32768 | W2 32768 | att 512]
// ---------------------------------------------------------------------------
__global__ __launch_bounds__(256) void cast_weights(
    const float* __restrict__ Wl, const float* __restrict__ Wr,
    const float* __restrict__ W1, const float* __restrict__ W2,
    const float* __restrict__ att, ushort* __restrict__ wb)
{
    int i = blockIdx.x * 256 + threadIdx.x;          // 770*256 == 197120 exact
    const float* src; int off;
    if (i < 65536)       { src = Wl;  off = i; }
    else if (i < 131072) { src = Wr;  off = i - 65536; }
    else if (i < 163840) { src = W1;  off = i - 131072; }
    else if (i < 196608) { src = W2;  off = i - 163840; }
    else                 { src = att; off = i - 196608; }
    wb[i] = f2bf(src[off]);
}

// ---------------------------------------------------------------------------
// Fused xl+xr GEMM. A = x (fp32, converted to bf16 while staging), stationary.
// Loops over 8 column-tiles of Wcat=[Wl;Wr] (1024x128 bf16, contiguous in wb).
// MFMA computes D = Bfrag x Afrag so each lane holds 4 CONSECUTIVE output
// cols -> ushort4 8B stores.  out: xlb/xrb [N,512] bf16.
// ---------------------------------------------------------------------------
__global__ __launch_bounds__(256) void gemm_lr(
    const float* __restrict__ x, const ushort* __restrict__ wcat,
    const float* __restrict__ bl, const float* __restrict__ br,
    ushort* __restrict__ xlb, ushort* __restrict__ xrb)
{
    __shared__ ushort As[128 * 128];
    __shared__ ushort Bs[128 * 128];
    const int tid  = threadIdx.x;
    const int rb   = blockIdx.x * 128;
    const int wave = tid >> 6, lane = tid & 63;
    const int wm   = (wave >> 1) * 64, wn = (wave & 1) * 64;
    const int lr   = lane & 15, lq = lane >> 4;

    // stage A: 128 rows x 128 fp32 -> bf16, swizzled 16B chunks
    #pragma unroll
    for (int i = 0; i < 8; ++i) {
        int chunk = tid + i * 256;          // 0..2047
        int rr = chunk >> 4, cc = chunk & 15;
        int gr = rb + rr;
        float4 v0 = make_float4(0.f,0.f,0.f,0.f), v1 = v0;
        if (gr < N_NODES) {
            v0 = *(const float4*)(x + (size_t)gr * 128 + cc * 8);
            v1 = *(const float4*)(x + (size_t)gr * 128 + cc * 8 + 4);
        }
        uint4 h = make_uint4(pk2(v0.x,v0.y), pk2(v0.z,v0.w),
                             pk2(v1.x,v1.y), pk2(v1.z,v1.w));
        *(uint4*)(As + rr * 128 + ((cc ^ (rr & 15)) * 8)) = h;
    }

    for (int cbk = 0; cbk < 8; ++cbk) {
        __syncthreads();                     // Bs safe to overwrite / As ready
        #pragma unroll
        for (int i = 0; i < 8; ++i) {
            int chunk = tid + i * 256;
            int rr = chunk >> 4, cc = chunk & 15;
            uint4 vb = *(const uint4*)(wcat + (size_t)(cbk * 128 + rr) * 128 + cc * 8);
            *(uint4*)(Bs + rr * 128 + ((cc ^ (rr & 15)) * 8)) = vb;
        }
        __syncthreads();

        f32x4 zero = {0.f,0.f,0.f,0.f};
        f32x4 acc[4][4];
        #pragma unroll
        for (int i = 0; i < 4; ++i)
            #pragma unroll
            for (int j = 0; j < 4; ++j) acc[i][j] = zero;

        #pragma unroll
        for (int q = 0; q < 4; ++q) {
            int csw = ((q * 4 + lq) ^ lr) * 8;
            bf16x8 bfr[4], af[4];
            #pragma unroll
            for (int i = 0; i < 4; ++i) {
                bfr[i] = *(const bf16x8*)(Bs + (wm + i * 16 + lr) * 128 + csw);
                af[i]  = *(const bf16x8*)(As + (wn + i * 16 + lr) * 128 + csw);
            }
            #pragma unroll
            for (int i = 0; i < 4; ++i)
                #pragma unroll
                for (int j = 0; j < 4; ++j)
                    acc[i][j] = __builtin_amdgcn_mfma_f32_16x16x32_bf16(
                        bfr[i], af[j], acc[i][j], 0, 0, 0);
        }

        const float* bias = (cbk < 4) ? bl : br;
        ushort* outp = (cbk < 4) ? xlb : xrb;
        const int cloc = (cbk & 3) * 128;
        #pragma unroll
        for (int i = 0; i < 4; ++i) {
            int wc = wm + i * 16 + lq * 4;   // col offset within 128-tile
            float4 bv = *(const float4*)(bias + cloc + wc);
            #pragma unroll
            for (int j = 0; j < 4; ++j) {
                int node = rb + wn + j * 16 + lr;
                if (node < N_NODES) {
                    ushort4 o;
                    o.x = f2bf(acc[i][j][0] + bv.x);
                    o.y = f2bf(acc[i][j][1] + bv.y);
                    o.z = f2bf(acc[i][j][2] + bv.z);
                    o.w = f2bf(acc[i][j][3] + bv.w);
                    *(ushort4*)(outp + (size_t)node * 512 + cloc + wc) = o;
                }
            }
        }
    }
}

// ---------------------------------------------------------------------------
// FFN1: tb = GELU(x1b @ W1^T + b1).  A bf16 [N,128], W1 [256,128]. 2 col-tiles.
// ---------------------------------------------------------------------------
__global__ __launch_bounds__(256) void gemm_ffn1(
    const ushort* __restrict__ A, const ushort* __restrict__ w1b,
    const float* __restrict__ b1, ushort* __restrict__ tb)
{
    __shared__ ushort As[128 * 128];
    __shared__ ushort Bs[128 * 128];
    const int tid  = threadIdx.x;
    const int rb   = blockIdx.x * 128;
    const int wave = tid >> 6, lane = tid & 63;
    const int wm   = (wave >> 1) * 64, wn = (wave & 1) * 64;
    const int lr   = lane & 15, lq = lane >> 4;

    #pragma unroll
    for (int i = 0; i < 8; ++i) {
        int chunk = tid + i * 256;
        int rr = chunk >> 4, cc = chunk & 15;
        int gr = rb + rr;
        uint4 va = make_uint4(0u,0u,0u,0u);
        if (gr < N_NODES) va = *(const uint4*)(A + (size_t)gr * 128 + cc * 8);
        *(uint4*)(As + rr * 128 + ((cc ^ (rr & 15)) * 8)) = va;
    }

    for (int cbk = 0; cbk < 2; ++cbk) {
        __syncthreads();
        #pragma unroll
        for (int i = 0; i < 8; ++i) {
            int chunk = tid + i * 256;
            int rr = chunk >> 4, cc = chunk & 15;
            uint4 vb = *(const uint4*)(w1b + (size_t)(cbk * 128 + rr) * 128 + cc * 8);
            *(uint4*)(Bs + rr * 128 + ((cc ^ (rr & 15)) * 8)) = vb;
        }
        __syncthreads();

        f32x4 zero = {0.f,0.f,0.f,0.f};
        f32x4 acc[4][4];
        #pragma unroll
        for (int i = 0; i < 4; ++i)
            #pragma unroll
            for (int j = 0; j < 4; ++j) acc[i][j] = zero;

        #pragma unroll
        for (int q = 0; q < 4; ++q) {
            int csw = ((q * 4 + lq) ^ lr) * 8;
            bf16x8 bfr[4], af[4];
            #pragma unroll
            for (int i = 0; i < 4; ++i) {
                bfr[i] = *(const bf16x8*)(Bs + (wm + i * 16 + lr) * 128 + csw);
                af[i]  = *(const bf16x8*)(As + (wn + i * 16 + lr) * 128 + csw);
            }
            #pragma unroll
            for (int i = 0; i < 4; ++i)
                #pragma unroll
                for (int j = 0; j < 4; ++j)
                    acc[i][j] = __builtin_amdgcn_mfma_f32_16x16x32_bf16(
                        bfr[i], af[j], acc[i][j], 0, 0, 0);
        }

        const int cloc = cbk * 128;
        #pragma unroll
        for (int i = 0; i < 4; ++i) {
            int wc = wm + i * 16 + lq * 4;
            float4 bv = *(const float4*)(b1 + cloc + wc);
            #pragma unroll
            for (int j = 0; j < 4; ++j) {
                int node = rb + wn + j * 16 + lr;
                if (node < N_NODES) {
                    float v[4];
                    v[0] = acc[i][j][0] + bv.x; v[1] = acc[i][j][1] + bv.y;
                    v[2] = acc[i][j][2] + bv.z; v[3] = acc[i][j][3] + bv.w;
                    ushort4 o;
                    #pragma unroll
                    for (int r = 0; r < 4; ++r)
                        v[r] = v[r] * 0.5f * (1.0f + erff(v[r] * 0.70710678118654752f));
                    o.x = f2bf(v[0]); o.y = f2bf(v[1]);
                    o.z = f2bf(v[2]); o.w = f2bf(v[3]);
                    *(ushort4*)(tb + (size_t)node * 256 + cloc + wc) = o;
                }
            }
        }
    }
}

// ---------------------------------------------------------------------------
// FFN2 + residual + LayerNorm2 fused.  h = tb @ W2^T + b2 (K=256, 128 cols);
// y = x1 + h; out = LN(y)*g2+be2.  Per-row stats via lane partials + 1KB LDS.
// ---------------------------------------------------------------------------
__global__ __launch_bounds__(256) void gemm_ffn2_ln(
    const ushort* __restrict__ tb, const ushort* __restrict__ w2b,
    const float* __restrict__ b2, const float* __restrict__ x1,
    const float* __restrict__ g2, const float* __restrict__ be2,
    float* __restrict__ out)
{
    __shared__ char smem[65536];
    ushort* As = (ushort*)smem;             // 32KB
    ushort* Bs = (ushort*)(smem + 32768);   // 32KB
    const int tid  = threadIdx.x;
    const int rb   = blockIdx.x * 128;
    const int wave = tid >> 6, lane = tid & 63;
    const int wm   = (wave >> 1) * 64, wn = (wave & 1) * 64;
    const int lr   = lane & 15, lq = lane >> 4;

    f32x4 zero = {0.f,0.f,0.f,0.f};
    f32x4 acc[4][4];
    #pragma unroll
    for (int i = 0; i < 4; ++i)
        #pragma unroll
        for (int j = 0; j < 4; ++j) acc[i][j] = zero;

    for (int k0 = 0; k0 < 256; k0 += 128) {
        __syncthreads();
        #pragma unroll
        for (int i = 0; i < 8; ++i) {
            int chunk = tid + i * 256;
            int rr = chunk >> 4, cc = chunk & 15;
            int gr = rb + rr;
            uint4 va = make_uint4(0u,0u,0u,0u);
            if (gr < N_NODES) va = *(const uint4*)(tb + (size_t)gr * 256 + k0 + cc * 8);
            *(uint4*)(As + rr * 128 + ((cc ^ (rr & 15)) * 8)) = va;
            uint4 vb = *(const uint4*)(w2b + (size_t)rr * 256 + k0 + cc * 8);
            *(uint4*)(Bs + rr * 128 + ((cc ^ (rr & 15)) * 8)) = vb;
        }
        __syncthreads();

        #pragma unroll
        for (int q = 0; q < 4; ++q) {
            int csw = ((q * 4 + lq) ^ lr) * 8;
            bf16x8 bfr[4], af[4];
            #pragma unroll
            for (int i = 0; i < 4; ++i) {
                bfr[i] = *(const bf16x8*)(Bs + (wm + i * 16 + lr) * 128 + csw);
                af[i]  = *(const bf16x8*)(As + (wn + i * 16 + lr) * 128 + csw);
            }
            #pragma unroll
            for (int i = 0; i < 4; ++i)
                #pragma unroll
                for (int j = 0; j < 4; ++j)
                    acc[i][j] = __builtin_amdgcn_mfma_f32_16x16x32_bf16(
                        bfr[i], af[j], acc[i][j], 0, 0, 0);
        }
    }

    __syncthreads();                         // smem now reusable for stats
    float* sums = (float*)smem;              // [2][128]
    float* ssqs = (float*)(smem + 1024);     // [2][128]

    // y = h + b2 + x1, stored back into acc; per-node partial sums
    #pragma unroll
    for (int j = 0; j < 4; ++j) {
        int node = rb + wn + j * 16 + lr;
        float s = 0.f, q2 = 0.f;
        #pragma unroll
        for (int i = 0; i < 4; ++i) {
            int wc = wm + i * 16 + lq * 4;
            float4 bv = *(const float4*)(b2 + wc);
            float4 xv = make_float4(0.f,0.f,0.f,0.f);
            if (node < N_NODES) xv = *(const float4*)(x1 + (size_t)node * 128 + wc);
            float y0 = acc[i][j][0] + bv.x + xv.x;
            float y1 = acc[i][j][1] + bv.y + xv.y;
            float y2 = acc[i][j][2] + bv.z + xv.z;
            float y3 = acc[i][j][3] + bv.w + xv.w;
            acc[i][j][0] = y0; acc[i][j][1] = y1;
            acc[i][j][2] = y2; acc[i][j][3] = y3;
            s  += y0 + y1 + y2 + y3;
            q2 += y0*y0 + y1*y1 + y2*y2 + y3*y3;
        }
        s  += __shfl_xor(s, 16, 64);  s  += __shfl_xor(s, 32, 64);
        q2 += __shfl_xor(q2, 16, 64); q2 += __shfl_xor(q2, 32, 64);
        if (lq == 0) {
            int half = wm >> 6;
            sums[half * 128 + wn + j * 16 + lr] = s;
            ssqs[half * 128 + wn + j * 16 + lr] = q2;
        }
    }
    __syncthreads();

    #pragma unroll
    for (int j = 0; j < 4; ++j) {
        int nl = wn + j * 16 + lr;
        int node = rb + nl;
        if (node >= N_NODES) continue;
        float tot = sums[nl] + sums[128 + nl];
        float tq  = ssqs[nl] + ssqs[128 + nl];
        float mu  = tot * (1.0f / 128.0f);
        float var = tq * (1.0f / 128.0f) - mu * mu;
        float rs  = rsqrtf(var + LN_EPS);
        #pragma unroll
        for (int i = 0; i < 4; ++i) {
            int wc = wm + i * 16 + lq * 4;
            float4 gv = *(const float4*)(g2 + wc);
            float4 ev = *(const float4*)(be2 + wc);
            float4 o;
            o.x = (acc[i][j][0] - mu) * rs * gv.x + ev.x;
            o.y = (acc[i][j][1] - mu) * rs * gv.y + ev.y;
            o.z = (acc[i][j][2] - mu) * rs * gv.z + ev.z;
            o.w = (acc[i][j][3] - mu) * rs * gv.w + ev.w;
            *(float4*)(out + (size_t)node * 128 + wc) = o;
        }
    }
}

// ---------------------------------------------------------------------------
// CSR build
// ---------------------------------------------------------------------------
__global__ __launch_bounds__(256) void count_deg(const int* __restrict__ dst,
                                                 int* __restrict__ counts)
{
    int i = blockIdx.x * 256 + threadIdx.x;
    if (i >= EN_TOT) return;
    int d = (i < N_EDGES) ? dst[i] : (i - N_EDGES);
    atomicAdd(counts + d, 1);
}

__global__ __launch_bounds__(64) void scan1(const int* __restrict__ counts,
                                            int* __restrict__ csum)
{
    int lane = threadIdx.x;
    int base = blockIdx.x * 512 + lane * 8;
    int s = 0;
    #pragma unroll
    for (int k = 0; k < 8; ++k) {
        int idx = base + k;
        if (idx < N_NODES) s += counts[idx];
    }
    #pragma unroll
    for (int m = 32; m; m >>= 1) s += __shfl_xor(s, m, 64);
    if (lane == 0) csum[blockIdx.x] = s;
}

__global__ __launch_bounds__(64) void scan2(int* __restrict__ csum,
                                            int* __restrict__ offs)
{
    int l = threadIdx.x;
    int v0 = (l < NC_SCAN) ? csum[l] : 0;
    int v1 = (l + 64 < NC_SCAN) ? csum[l + 64] : 0;
    int s0 = v0;
    #pragma unroll
    for (int d = 1; d < 64; d <<= 1) {
        int t = __shfl_up(s0, d, 64);
        if (l >= d) s0 += t;
    }
    int tot0 = __shfl(s0, 63, 64);
    int s1 = v1;
    #pragma unroll
    for (int d = 1; d < 64; d <<= 1) {
        int t = __shfl_up(s1, d, 64);
        if (l >= d) s1 += t;
    }
    int tot1 = __shfl(s1, 63, 64);
    if (l < NC_SCAN) csum[l] = s0 - v0;
    if (l + 64 < NC_SCAN) csum[l + 64] = tot0 + s1 - v1;
    if (l == 0) offs[N_NODES] = tot0 + tot1;
}

__global__ __launch_bounds__(64) void scan3(const int* __restrict__ counts,
                                            const int* __restrict__ csum,
                                            int* __restrict__ offs)
{
    int lane = threadIdx.x;
    int base = blockIdx.x * 512 + lane * 8;
    int cnt[8];
    int s = 0;
    #pragma unroll
    for (int k = 0; k < 8; ++k) {
        int idx = base + k;
        cnt[k] = (idx < N_NODES) ? counts[idx] : 0;
        s += cnt[k];
    }
    int inc = s;
    #pragma unroll
    for (int d = 1; d < 64; d <<= 1) {
        int t = __shfl_up(inc, d, 64);
        if (lane >= d) inc += t;
    }
    int run = csum[blockIdx.x] + (inc - s);
    #pragma unroll
    for (int k = 0; k < 8; ++k) {
        int idx = base + k;
        if (idx < N_NODES) { offs[idx] = run; run += cnt[k]; }
    }
}

__global__ __launch_bounds__(256) void scatter_edges(
    const int* __restrict__ src, const int* __restrict__ dst,
    const int* __restrict__ offs, int* __restrict__ cursor,
    int* __restrict__ srcList)
{
    int i = blockIdx.x * 256 + threadIdx.x;
    if (i >= EN_TOT) return;
    int s, d;
    if (i < N_EDGES) { s = src[i]; d = dst[i]; }
    else             { s = d = i - N_EDGES; }
    int pos = atomicAdd(cursor + d, 1);
    srcList[offs[d] + pos] = s;
}

// ---------------------------------------------------------------------------
// GATv2 per destination node (one wave each), bf16 gather (unchanged R1).
// ---------------------------------------------------------------------------
__global__ __launch_bounds__(256) void gat_fused(
    const float* __restrict__ x, const ushort* __restrict__ xl,
    const ushort* __restrict__ xr, const int* __restrict__ offs,
    const int* __restrict__ srcList, const ushort* __restrict__ attb,
    const float* __restrict__ bias, const float* __restrict__ g1,
    const float* __restrict__ be1, float* __restrict__ x1,
    ushort* __restrict__ x1b)
{
    const int wave = threadIdx.x >> 6;
    const int lane = threadIdx.x & 63;
    const int v = blockIdx.x * 4 + wave;
    if (v >= N_NODES) return;

    uint4 rw = *(const uint4*)(xr + (size_t)v * 512 + lane * 8);
    uint4 aw = *(const uint4*)(attb + lane * 8);
    float r[8], at[8];
    r[0]=bf_lo(rw.x); r[1]=bf_hi(rw.x); r[2]=bf_lo(rw.y); r[3]=bf_hi(rw.y);
    r[4]=bf_lo(rw.z); r[5]=bf_hi(rw.z); r[6]=bf_lo(rw.w); r[7]=bf_hi(rw.w);
    at[0]=bf_lo(aw.x); at[1]=bf_hi(aw.x); at[2]=bf_lo(aw.y); at[3]=bf_hi(aw.y);
    at[4]=bf_lo(aw.z); at[5]=bf_hi(aw.z); at[6]=bf_lo(aw.w); at[7]=bf_hi(aw.w);

    float acc[8] = {0.f,0.f,0.f,0.f,0.f,0.f,0.f,0.f};
    float lh = 0.f;

    const int jb = offs[v], je = offs[v + 1];
    uint4 cur = *(const uint4*)(xl + (size_t)srcList[jb] * 512 + lane * 8);
    for (int j = jb; j < je; ++j) {
        int jn = (j + 1 < je) ? (j + 1) : j;
        uint4 nxt = *(const uint4*)(xl + (size_t)srcList[jn] * 512 + lane * 8);

        float b[8];
        b[0]=bf_lo(cur.x); b[1]=bf_hi(cur.x); b[2]=bf_lo(cur.y); b[3]=bf_hi(cur.y);
        b[4]=bf_lo(cur.z); b[5]=bf_hi(cur.z); b[6]=bf_lo(cur.w); b[7]=bf_hi(cur.w);
        float p = 0.f;
        #pragma unroll
        for (int k = 0; k < 8; ++k) {
            float s  = b[k] + r[k];
            float lr2 = fmaxf(s, 0.f) + NEG_SLOPE * fminf(s, 0.f);
            p = fmaf(lr2, at[k], p);
        }
        p += __shfl_xor(p, 1, 64);
        p += __shfl_xor(p, 2, 64);
        p += __shfl_xor(p, 4, 64);
        p += __shfl_xor(p, 8, 64);
        float w = __expf(p);
        lh += w;
        #pragma unroll
        for (int k = 0; k < 8; ++k) acc[k] = fmaf(w, b[k], acc[k]);
        cur = nxt;
    }

    const float inv = 1.0f / lh;
    const int d0 = (lane & 15) * 8;
    const size_t xo = (size_t)v * 128 + d0;

    float4 xv0 = *(const float4*)(x + xo);
    float4 xv1 = *(const float4*)(x + xo + 4);
    float4 bb0 = *(const float4*)(bias + d0);
    float4 bb1 = *(const float4*)(bias + d0 + 4);
    float xr8[8] = {xv0.x,xv0.y,xv0.z,xv0.w,xv1.x,xv1.y,xv1.z,xv1.w};
    float bi8[8] = {bb0.x,bb0.y,bb0.z,bb0.w,bb1.x,bb1.y,bb1.z,bb1.w};

    float y[8];
    float s = 0.f;
    #pragma unroll
    for (int k = 0; k < 8; ++k) {
        float o = acc[k] * inv;
        o += __shfl_xor(o, 16, 64);
        o += __shfl_xor(o, 32, 64);
        float yy = xr8[k] + o * 0.25f + bi8[k];
        y[k] = yy;
        s += yy;
    }
    s += __shfl_xor(s, 1, 64);
    s += __shfl_xor(s, 2, 64);
    s += __shfl_xor(s, 4, 64);
    s += __shfl_xor(s, 8, 64);
    float mu = s * (1.0f / 128.0f);
    float ss = 0.f;
    #pragma unroll
    for (int k = 0; k < 8; ++k) { float d = y[k] - mu; ss += d * d; }
    ss += __shfl_xor(ss, 1, 64);
    ss += __shfl_xor(ss, 2, 64);
    ss += __shfl_xor(ss, 4, 64);
    ss += __shfl_xor(ss, 8, 64);
    float rs = rsqrtf(ss * (1.0f / 128.0f) + LN_EPS);

    if ((lane >> 4) == 0) {
        float4 g0 = *(const float4*)(g1 + d0);
        float4 g4 = *(const float4*)(g1 + d0 + 4);
        float4 e0 = *(const float4*)(be1 + d0);
        float4 e4 = *(const float4*)(be1 + d0 + 4);
        float gg[8] = {g0.x,g0.y,g0.z,g0.w,g4.x,g4.y,g4.z,g4.w};
        float ee[8] = {e0.x,e0.y,e0.z,e0.w,e4.x,e4.y,e4.z,e4.w};
        float z[8];
        ushort4 zb0, zb1;
        #pragma unroll
        for (int k = 0; k < 8; ++k) z[k] = (y[k] - mu) * rs * gg[k] + ee[k];
        *(float4*)(x1 + xo)     = make_float4(z[0], z[1], z[2], z[3]);
        *(float4*)(x1 + xo + 4) = make_float4(z[4], z[5], z[6], z[7]);
        zb0.x=f2bf(z[0]); zb0.y=f2bf(z[1]); zb0.z=f2bf(z[2]); zb0.w=f2bf(z[3]);
        zb1.x=f2bf(z[4]); zb1.y=f2bf(z[5]); zb1.z=f2bf(z[6]); zb1.w=f2bf(z[7]);
        *(ushort4*)(x1b + xo)     = zb0;
        *(ushort4*)(x1b + xo + 4) = zb1;
    }
}

// ---------------------------------------------------------------------------
extern "C" void kernel_launch(void* const* d_in, const int* in_sizes, int n_in,
                              void* d_out, int out_size, void* d_ws, size_t ws_size,
                              hipStream_t stream)
{
    const float* x    = (const float*)d_in[0];
    const int*   ei   = (const int*)  d_in[1];
    const float* Wl   = (const float*)d_in[2];
    const float* bl   = (const float*)d_in[3];
    const float* Wr   = (const float*)d_in[4];
    const float* br   = (const float*)d_in[5];
    const float* att  = (const float*)d_in[6];
    const float* bias = (const float*)d_in[7];
    const float* g1   = (const float*)d_in[8];
    const float* be1  = (const float*)d_in[9];
    const float* W1   = (const float*)d_in[10];
    const float* b1   = (const float*)d_in[11];
    const float* W2   = (const float*)d_in[12];
    const float* b2   = (const float*)d_in[13];
    const float* g2   = (const float*)d_in[14];
    const float* be2  = (const float*)d_in[15];
    float* out = (float*)d_out;

    char* ws = (char*)d_ws;
    size_t off = 0;
    auto alloc = [&](size_t bytes) -> void* {
        void* p = ws + off;
        off = (off + bytes + 255) & ~(size_t)255;
        return p;
    };
    ushort* xlb  = (ushort*)alloc((size_t)N_NODES * 512 * 2);
    ushort* xrb  = (ushort*)alloc((size_t)N_NODES * 512 * 2);
    float*  x1   = (float*) alloc((size_t)N_NODES * 128 * 4);
    ushort* x1b  = (ushort*)alloc((size_t)N_NODES * 128 * 2);
    ushort* tb   = (ushort*)alloc((size_t)N_NODES * 256 * 2);
    ushort* wb   = (ushort*)alloc((size_t)197120 * 2);
    int*   offs    = (int*)alloc((size_t)(N_NODES + 1) * 4);
    int*   counts  = (int*)alloc((size_t)N_NODES * 4 * 2);
    int*   cursor  = counts + N_NODES;
    int*   csum    = (int*)alloc(512);
    int*   srcList = (int*)alloc((size_t)EN_TOT * 4);

    ushort* wcat = wb;              // [Wl;Wr] 1024x128
    ushort* w1b  = wb + 131072;
    ushort* w2b  = wb + 163840;
    ushort* attb = wb + 196608;

    hipMemsetAsync(counts, 0, (size_t)N_NODES * 8, stream);

    cast_weights<<<770, 256, 0, stream>>>(Wl, Wr, W1, W2, att, wb);

    gemm_lr<<<391, 256, 0, stream>>>(x, wcat, bl, br, xlb, xrb);

    count_deg<<<(EN_TOT + 255) / 256, 256, 0, stream>>>(ei + N_EDGES, counts);
    scan1<<<NC_SCAN, 64, 0, stream>>>(counts, csum);
    scan2<<<1, 64, 0, stream>>>(csum, offs);
    scan3<<<NC_SCAN, 64, 0, stream>>>(counts, csum, offs);
    scatter_edges<<<(EN_TOT + 255) / 256, 256, 0, stream>>>(ei, ei + N_EDGES,
                                                           offs, cursor, srcList);

    gat_fused<<<12500, 256, 0, stream>>>(x, xlb, xrb, offs, srcList, attb,
                                         bias, g1, be1, x1, x1b);

    gemm_ffn1<<<391, 256, 0, stream>>>(x1b, w1b, b1, tb);
    gemm_ffn2_ln<<<391, 256, 0, stream>>>(tb, w2b, b2, x1, g2, be2, out);
}